// Round 10
// baseline (1195.282 us; speedup 1.0000x reference)
//
#include <hip/hip_runtime.h>

// ---------------------------------------------------------------------------
// SubModel_22016002359901: 3x GCN(2 conv) + FC heads, N=100000, F=128, E=1.6M
// Round 10: gather v2 -- 4 edges per wave (16 lanes x 8 features each, 16B
// h-loads, 4x fewer VMEM instrs + 4x fewer loop iters), butterfly combine.
// GEMM grid transposed so col-tiles are dispatch-adjacent (A-tile L2 reuse
// for M=256 GEMMs). CSR build unchanged from round 9.
// ---------------------------------------------------------------------------

typedef short bf16x8 __attribute__((ext_vector_type(8)));
typedef float f32x4 __attribute__((ext_vector_type(4)));

#define BSHIFT 8                 // 256 dst nodes per bucket
#define NBUCK_MAX 400
#define BCAP 6144                // mean 4096 @ E=1.6M, sigma ~64 -> 32 sigma headroom
#define WDSCALE 8388608.f        // 2^23 fixed-point for weighted degree

static __device__ __forceinline__ float frelu(float x) { return x > 0.f ? x : 0.f; }

static __device__ __forceinline__ unsigned short f2bf(float f) {
    unsigned int u = __float_as_uint(f);
    u += 0x7fffu + ((u >> 16) & 1u);           // RNE
    return (unsigned short)(u >> 16);
}
static __device__ __forceinline__ float bflo(unsigned int u) {
    return __uint_as_float(u << 16);
}
static __device__ __forceinline__ float bfhi(unsigned int u) {
    return __uint_as_float(u & 0xffff0000u);
}

// ---------------- conversion kernels ----------------
__global__ void xconv(const float* __restrict__ src, unsigned short* __restrict__ dst, int n4) {
    int i = blockIdx.x * 256 + threadIdx.x;
    if (i >= n4) return;
    float4 v = *(const float4*)(src + (size_t)i * 4);
    ushort4 o = {f2bf(v.x), f2bf(v.y), f2bf(v.z), f2bf(v.w)};
    *(ushort4*)(dst + (size_t)i * 4) = o;
}

__global__ void wtrans(const float* __restrict__ src, unsigned short* __restrict__ dst,
                       int K, int M) {
    int i = blockIdx.x * 256 + threadIdx.x;
    if (i >= K * M) return;
    int m = i / K, k = i % K;
    dst[i] = f2bf(src[(size_t)k * M + m]);
}

__global__ void zero_small(int* __restrict__ p, int n) {
    int i = blockIdx.x * 256 + threadIdx.x;
    if (i < n) p[i] = 0;
}

// ---------------- bucketed edge partition ----------------
// record = {src | dstlocal<<17, ew}; bucket = dst>>8
__global__ __launch_bounds__(256) void part_k(
    const int* __restrict__ src, const int* __restrict__ dst,
    const float* __restrict__ ew, int* __restrict__ gcur,
    int2* __restrict__ part, int nE, int nbuck) {
    __shared__ int lh[NBUCK_MAX];
    __shared__ int gb[NBUCK_MAX];
    const int tid = threadIdx.x;
    for (int t = tid; t < nbuck; t += 256) lh[t] = 0;
    __syncthreads();
    const int e0 = blockIdx.x * 4096;
    int rk[16], bk[16];
#pragma unroll
    for (int j = 0; j < 16; ++j) {
        int e = e0 + j * 256 + tid;
        rk[j] = -1;
        if (e < nE) {
            int b = dst[e] >> BSHIFT;
            bk[j] = b;
            rk[j] = atomicAdd(&lh[b], 1);
        }
    }
    __syncthreads();
    for (int t = tid; t < nbuck; t += 256)
        gb[t] = lh[t] ? atomicAdd(&gcur[t], lh[t]) : 0;
    __syncthreads();
#pragma unroll
    for (int j = 0; j < 16; ++j) {
        int e = e0 + j * 256 + tid;
        if (e >= nE) continue;
        int b = bk[j];
        int slot = gb[b] + rk[j];
        if (slot >= 0 && slot < BCAP) {
            int s = src[e];
            int dl = dst[e] & ((1 << BSHIFT) - 1);
            part[(size_t)b * BCAP + slot] = make_int2(s | (dl << 17), __float_as_int(ew[e]));
        }
    }
}

// exclusive scan of clamped bucket counts -> bbase; rp[n] = total
__global__ void scanB(const int* __restrict__ gcur, int* __restrict__ bbase,
                      int* __restrict__ rp, int n, int nbuck) {
    __shared__ int s[512];
    int t = threadIdx.x;
    int c = (t < nbuck) ? gcur[t] : 0;
    if (c > BCAP) c = BCAP;
    s[t] = c;
    __syncthreads();
#pragma unroll
    for (int off = 1; off < 512; off <<= 1) {
        int x = (t >= off) ? s[t - off] : 0;
        __syncthreads();
        s[t] += x;
        __syncthreads();
    }
    if (t < nbuck) bbase[t] = s[t] - c;        // exclusive
    if (t == nbuck - 1) rp[n] = s[t];          // total (== E unless overflow)
}

// one 256-thread block per bucket: LDS counting sort by dstlocal ->
// ev records {src, ew}; fixed-point weighted degree fused -> dinv; rp.
__global__ __launch_bounds__(256) void csr_bucket(
    const int2* __restrict__ part, const int* __restrict__ gcur,
    const int* __restrict__ bbase, int2* __restrict__ ev,
    int* __restrict__ rp, float* __restrict__ dinv, int n) {
    __shared__ int hist[256];
    __shared__ int cur[256];
    __shared__ int wd[256];
    const int b = blockIdx.x;
    const int t = threadIdx.x;
    int cnt = gcur[b];
    if (cnt > BCAP) cnt = BCAP;
    const int gbase = bbase[b];
    const int2* pb = part + (size_t)b * BCAP;

    hist[t] = 0; wd[t] = 0;
    __syncthreads();
    for (int i = t; i < cnt; i += 256)
        atomicAdd(&hist[(pb[i].x >> 17) & 255], 1);
    __syncthreads();
    int myh = hist[t];
#pragma unroll
    for (int off = 1; off < 256; off <<= 1) {
        int x = (t >= off) ? hist[t - off] : 0;
        __syncthreads();
        hist[t] += x;
        __syncthreads();
    }
    int excl = hist[t] - myh;
    cur[t] = excl;
    __syncthreads();
    for (int i = t; i < cnt; i += 256) {
        int2 p = pb[i];
        int dl = (p.x >> 17) & 255;
        int pos = atomicAdd(&cur[dl], 1);
        ev[(size_t)gbase + pos] = make_int2(p.x & 0x1FFFF, p.y);
        atomicAdd(&wd[dl], (int)(__int_as_float(p.y) * WDSCALE + 0.5f));
    }
    __syncthreads();
    int g = (b << BSHIFT) + t;
    if (g < n) {
        dinv[g] = rsqrtf(1.f + (float)wd[t] * (1.f / WDSCALE));
        rp[g] = gbase + excl;
    }
}

// gather v2: one wave per node, 4 edges in flight (16 lanes x 8 features each).
// aggr = relu( dinv[n]*sum(dinv[src]*ew*h[src]) + dinv[n]^2*h[n] + bias )
__global__ __launch_bounds__(256) void gather_bf(
    const int* __restrict__ rp, const int2* __restrict__ ev,
    const unsigned short* __restrict__ h,
    const float* __restrict__ dinv, const float* __restrict__ bias,
    unsigned short* __restrict__ aggr, int n) {
    int node = (int)(((size_t)blockIdx.x * 256 + threadIdx.x) >> 6);
    if (node >= n) return;
    const int lane = threadIdx.x & 63;
    const int grp  = lane >> 4;        // edge slot 0..3
    const int fl   = lane & 15;        // feature block: fl*8 .. fl*8+7

    float acc[8];
#pragma unroll
    for (int j = 0; j < 8; ++j) acc[j] = 0.f;

    const int beg = rp[node], end = rp[node + 1];
    for (int i = beg; i < end; i += 4) {
        int e = i + grp;
        bool v = e < end;
        int2 r = ev[v ? e : beg];
        float nm = v ? dinv[r.x] * __int_as_float(r.y) : 0.f;
        uint4 u = *(const uint4*)(h + (size_t)r.x * 128 + fl * 8);
        acc[0] += nm * bflo(u.x); acc[1] += nm * bfhi(u.x);
        acc[2] += nm * bflo(u.y); acc[3] += nm * bfhi(u.y);
        acc[4] += nm * bflo(u.z); acc[5] += nm * bfhi(u.z);
        acc[6] += nm * bflo(u.w); acc[7] += nm * bfhi(u.w);
    }
    // combine the 4 edge-groups (lanes L, L+16, L+32, L+48 hold same features)
#pragma unroll
    for (int j = 0; j < 8; ++j) acc[j] += __shfl_xor(acc[j], 16, 64);
#pragma unroll
    for (int j = 0; j < 8; ++j) acc[j] += __shfl_xor(acc[j], 32, 64);

    if (grp == 0) {
        float di = dinv[node];
        float sl = di * di;
        uint4 hu = *(const uint4*)(h + (size_t)node * 128 + fl * 8);
        float4 b0 = *(const float4*)(bias + fl * 8);
        float4 b1 = *(const float4*)(bias + fl * 8 + 4);
        float hx[8] = {bflo(hu.x), bfhi(hu.x), bflo(hu.y), bfhi(hu.y),
                       bflo(hu.z), bfhi(hu.z), bflo(hu.w), bfhi(hu.w)};
        float bb[8] = {b0.x, b0.y, b0.z, b0.w, b1.x, b1.y, b1.z, b1.w};
        unsigned int pk[4];
#pragma unroll
        for (int j = 0; j < 4; ++j) {
            float o0 = frelu(di * acc[2 * j]     + sl * hx[2 * j]     + bb[2 * j]);
            float o1 = frelu(di * acc[2 * j + 1] + sl * hx[2 * j + 1] + bb[2 * j + 1]);
            pk[j] = (unsigned int)f2bf(o0) | ((unsigned int)f2bf(o1) << 16);
        }
        *(uint4*)(aggr + (size_t)node * 128 + fl * 8) =
            make_uint4(pk[0], pk[1], pk[2], pk[3]);
    }
}

// ---------------- bf16 MFMA GEMM ----------------
// BM=128, BK=64, BN in {64,128}. 4 waves: wave tile 64 x BN/2.
// Grid: (cols/BN, rows/BM) -- col-tiles dispatch-adjacent for A L2 reuse.
// EPI: 0 = bf16 store; 1 = f32 store; 2 = f32 store + xs[row*64+col] += v.
template<int K, int BN, int RELU, int EPI>
__global__ __launch_bounds__(256, 2) void gemm_bf(
    const unsigned short* __restrict__ A, const unsigned short* __restrict__ Wt,
    const float* __restrict__ bias, void* __restrict__ Cout,
    int M, int nrows, float* __restrict__ xs) {
    constexpr int BM = 128, BK = 64;
    constexpr int WN = BN / 2;        // wave cols
    constexpr int NF = WN / 16;       // col fragments per wave (2 or 4)
    static_assert(BN == 64 || BN == 128, "BN");
    __shared__ unsigned short As[BM][BK + 8];
    __shared__ unsigned short Bs[BN][BK + 8];

    const int tid  = threadIdx.x;
    const int wid  = tid >> 6;
    const int lane = tid & 63;
    const int wm   = (wid >> 1) * 64;
    const int wn   = (wid & 1) * WN;
    const int row0 = blockIdx.y * BM;
    const int col0 = blockIdx.x * BN;
    const int lr   = lane & 15;
    const int lk   = (lane >> 4) * 8;

    f32x4 acc[4][NF] = {};

    for (int k0 = 0; k0 < K; k0 += BK) {
#pragma unroll
        for (int it = 0; it < 4; ++it) {                    // A: 128 rows x 8 granules
            int f = tid + it * 256;
            int r = f >> 3, g = f & 7;
            int grow = row0 + r;
            if (grow >= nrows) grow = nrows - 1;
            bf16x8 v = *(const bf16x8*)(A + (size_t)grow * K + k0 + g * 8);
            *(bf16x8*)&As[r][g * 8] = v;
        }
#pragma unroll
        for (int it = 0; it < BN / 32; ++it) {              // B: BN rows x 8 granules
            int f = tid + it * 256;
            int nidx = f >> 3, g = f & 7;
            bf16x8 v = *(const bf16x8*)(Wt + (size_t)(col0 + nidx) * K + k0 + g * 8);
            *(bf16x8*)&Bs[nidx][g * 8] = v;
        }
        __syncthreads();
#pragma unroll
        for (int kk = 0; kk < 2; ++kk) {
            bf16x8 af[4], bfv[NF];
#pragma unroll
            for (int mi = 0; mi < 4; ++mi)
                af[mi] = *(const bf16x8*)&As[wm + 16 * mi + lr][kk * 32 + lk];
#pragma unroll
            for (int ni = 0; ni < NF; ++ni)
                bfv[ni] = *(const bf16x8*)&Bs[wn + 16 * ni + lr][kk * 32 + lk];
#pragma unroll
            for (int mi = 0; mi < 4; ++mi)
#pragma unroll
                for (int ni = 0; ni < NF; ++ni)
                    acc[mi][ni] = __builtin_amdgcn_mfma_f32_16x16x32_bf16(
                        af[mi], bfv[ni], acc[mi][ni], 0, 0, 0);
        }
        __syncthreads();
    }

    const int dr0 = (lane >> 4) * 4;
#pragma unroll
    for (int ni = 0; ni < NF; ++ni) {
        int col = col0 + wn + 16 * ni + lr;
        float bv = bias ? bias[col] : 0.f;
#pragma unroll
        for (int mi = 0; mi < 4; ++mi) {
#pragma unroll
            for (int r = 0; r < 4; ++r) {
                int grow = row0 + wm + 16 * mi + dr0 + r;
                if (grow >= nrows) continue;
                float v = acc[mi][ni][r] + bv;
                if (RELU) v = frelu(v);
                if (EPI == 0) {
                    ((unsigned short*)Cout)[(size_t)grow * M + col] = f2bf(v);
                } else {
                    ((float*)Cout)[(size_t)grow * M + col] = v;
                    if (EPI == 2) xs[(size_t)grow * 64 + col] += v;
                }
            }
        }
    }
}

// ---------------------------------------------------------------------------
extern "C" void kernel_launch(void* const* d_in, const int* in_sizes, int n_in,
                              void* d_out, int out_size, void* d_ws, size_t ws_size,
                              hipStream_t stream) {
    (void)n_in; (void)out_size; (void)ws_size;
    const float* X = (const float*)d_in[0];
    const int N = in_sizes[0] / 128;

    const float* fc1_w1 = (const float*)d_in[19];
    const float* fc1_b1 = (const float*)d_in[20];
    const float* fc1_w2 = (const float*)d_in[21];
    const float* fc1_b2 = (const float*)d_in[22];
    const float* fc1_w3 = (const float*)d_in[23];
    const float* fc1_b3 = (const float*)d_in[24];
    const float* fc2_w1 = (const float*)d_in[25];
    const float* fc2_b1 = (const float*)d_in[26];
    const float* fc2_w2 = (const float*)d_in[27];
    const float* fc2_b2 = (const float*)d_in[28];
    const float* fc2_w3 = (const float*)d_in[29];
    const float* fc2_b3 = (const float*)d_in[30];

    float* out = (float*)d_out;
    float* Xs  = out;  // slot 0

    // ---- workspace layout ----
    char* base = (char*)d_ws;
    const size_t Npad = (((size_t)N + 255) / 256) * 256;
    float*          dinv  = (float*)base;                 base += Npad * 4;
    unsigned short* Xbf   = (unsigned short*)base;        base += (size_t)N * 128 * 2;
    unsigned short* t1bf  = (unsigned short*)base;        base += (size_t)N * 256 * 2;  // CSR arena alias
    unsigned short* t2bf  = (unsigned short*)base;        base += (size_t)N * 128 * 2;
    unsigned short* aggbf = (unsigned short*)base;        base += (size_t)N * 128 * 2;
    unsigned short* wtbuf = (unsigned short*)base;

    unsigned short* fc1w1t = wtbuf;
    unsigned short* fc1w2t = fc1w1t + 32768;
    unsigned short* fc1w3t = fc1w2t + 32768;
    unsigned short* fc2w1t = fc1w3t + 8192;
    unsigned short* fc2w2t = fc2w1t + 32768;
    unsigned short* fc2w3t = fc2w2t + 32768;
    unsigned short* gwt    = fc2w3t + 8192;

    const dim3 blk(256);
    const int GR = (N + 127) / 128;
    const int NBUCK = (N + 255) >> 8;     // 391 for N=100000
    const int GWB = (int)(((size_t)N * 64 + 255) / 256);

    // ---- one-time conversions ----
    xconv<<<(N * 32 + 255) / 256, blk, 0, stream>>>(X, Xbf, N * 32);
    wtrans<<<(128 * 256 + 255) / 256, blk, 0, stream>>>(fc1_w1, fc1w1t, 128, 256);
    wtrans<<<(256 * 128 + 255) / 256, blk, 0, stream>>>(fc1_w2, fc1w2t, 256, 128);
    wtrans<<<(128 * 64 + 255) / 256, blk, 0, stream>>>(fc1_w3, fc1w3t, 128, 64);
    wtrans<<<(128 * 256 + 255) / 256, blk, 0, stream>>>(fc2_w1, fc2w1t, 128, 256);
    wtrans<<<(256 * 128 + 255) / 256, blk, 0, stream>>>(fc2_w2, fc2w2t, 256, 128);
    wtrans<<<(128 * 64 + 255) / 256, blk, 0, stream>>>(fc2_w3, fc2w3t, 128, 64);
    for (int g = 0; g < 3; ++g) {
        wtrans<<<(128 * 128 + 255) / 256, blk, 0, stream>>>(
            (const float*)d_in[3 + 6 * g], gwt + g * 32768, 128, 128);
        wtrans<<<(128 * 128 + 255) / 256, blk, 0, stream>>>(
            (const float*)d_in[5 + 6 * g], gwt + g * 32768 + 16384, 128, 128);
    }

    // ---- X0 = fc1(X) -> Xs ----
    gemm_bf<128, 128, 1, 0><<<dim3(2, GR), blk, 0, stream>>>(Xbf, fc1w1t, fc1_b1, t1bf, 256, N, nullptr);
    gemm_bf<256, 128, 1, 0><<<dim3(1, GR), blk, 0, stream>>>(t1bf, fc1w2t, fc1_b2, t2bf, 128, N, nullptr);
    gemm_bf<128, 64, 1, 1><<<dim3(1, GR), blk, 0, stream>>>(t2bf, fc1w3t, fc1_b3, Xs, 64, N, nullptr);

    // ---- graphs ----
    for (int g = 0; g < 3; ++g) {
        const int*   ei  = (const int*)d_in[1 + 6 * g];
        const int    E   = in_sizes[1 + 6 * g] / 2;
        const int*   srp = ei;
        const int*   dsp = ei + E;
        const float* ew  = (const float*)d_in[2 + 6 * g];
        const float* b1  = (const float*)d_in[4 + 6 * g];
        const float* b2  = (const float*)d_in[6 + 6 * g];
        unsigned short* w1t = gwt + g * 32768;
        unsigned short* w2t = w1t + 16384;

        // CSR arena aliases t1bf (dead during conv phase)
        int2* part  = (int2*)t1bf;                        // NBUCK * BCAP  (19.2 MB)
        int2* ev    = part + (size_t)NBUCK * BCAP;        // E             (12.8 MB)
        int*  rpn   = (int*)(ev + E);                     // N+1
        int*  gcur  = rpn + (N + 1);                      // NBUCK
        int*  bbase = gcur + NBUCK;                       // NBUCK

        zero_small<<<(NBUCK + 255) / 256, blk, 0, stream>>>(gcur, NBUCK);
        part_k<<<(E + 4095) / 4096, blk, 0, stream>>>(srp, dsp, ew, gcur, part, E, NBUCK);
        scanB<<<1, 512, 0, stream>>>(gcur, bbase, rpn, N, NBUCK);
        csr_bucket<<<NBUCK, blk, 0, stream>>>(part, gcur, bbase, ev, rpn, dinv, N);

        // conv1 + conv2 (gather applies dinv scaling + self-loop + bias + relu)
        gemm_bf<128, 128, 0, 0><<<dim3(1, GR), blk, 0, stream>>>(Xbf, w1t, nullptr, t2bf, 128, N, nullptr);
        gather_bf<<<GWB, blk, 0, stream>>>(rpn, ev, t2bf, dinv, b1, aggbf, N);
        gemm_bf<128, 128, 0, 0><<<dim3(1, GR), blk, 0, stream>>>(aggbf, w2t, nullptr, t2bf, 128, N, nullptr);
        gather_bf<<<GWB, blk, 0, stream>>>(rpn, ev, t2bf, dinv, b2, aggbf, N);

        // fc2 head
        gemm_bf<128, 128, 1, 0><<<dim3(2, GR), blk, 0, stream>>>(aggbf, fc2w1t, fc2_b1, t1bf, 256, N, nullptr);
        gemm_bf<256, 128, 1, 0><<<dim3(1, GR), blk, 0, stream>>>(t1bf, fc2w2t, fc2_b2, t2bf, 128, N, nullptr);
        gemm_bf<128, 64, 1, 2><<<dim3(1, GR), blk, 0, stream>>>(
            t2bf, fc2w3t, fc2_b3, out + (size_t)(1 + g) * N * 64, 64, N, Xs);
    }
}

// Round 11
// 1098.596 us; speedup vs baseline: 1.0880x; 1.0880x over previous
//
#include <hip/hip_runtime.h>

// ---------------------------------------------------------------------------
// SubModel_22016002359901: 3x GCN(2 conv) + FC heads, N=100000, F=128, E=1.6M
// Round 11: round-9 base (best, 1133us) +
//   (1) gather v1 with 8-deep ILP (8 independent h-row loads in flight),
//   (2) part_k with wave-private LDS histograms (4x less LDS-atomic contention).
// GEMMs / CSR sort / everything else identical to round 9.
// ---------------------------------------------------------------------------

typedef short bf16x8 __attribute__((ext_vector_type(8)));
typedef float f32x4 __attribute__((ext_vector_type(4)));

#define BSHIFT 8                 // 256 dst nodes per bucket
#define NBUCK_MAX 400
#define BCAP 6144                // mean 4096 @ E=1.6M, sigma ~64 -> 32 sigma headroom
#define WDSCALE 8388608.f        // 2^23 fixed-point for weighted degree

static __device__ __forceinline__ float frelu(float x) { return x > 0.f ? x : 0.f; }

static __device__ __forceinline__ unsigned short f2bf(float f) {
    unsigned int u = __float_as_uint(f);
    u += 0x7fffu + ((u >> 16) & 1u);           // RNE
    return (unsigned short)(u >> 16);
}
static __device__ __forceinline__ float bflo(unsigned int u) {
    return __uint_as_float(u << 16);
}
static __device__ __forceinline__ float bfhi(unsigned int u) {
    return __uint_as_float(u & 0xffff0000u);
}

// ---------------- conversion kernels ----------------
__global__ void xconv(const float* __restrict__ src, unsigned short* __restrict__ dst, int n4) {
    int i = blockIdx.x * 256 + threadIdx.x;
    if (i >= n4) return;
    float4 v = *(const float4*)(src + (size_t)i * 4);
    ushort4 o = {f2bf(v.x), f2bf(v.y), f2bf(v.z), f2bf(v.w)};
    *(ushort4*)(dst + (size_t)i * 4) = o;
}

__global__ void wtrans(const float* __restrict__ src, unsigned short* __restrict__ dst,
                       int K, int M) {
    int i = blockIdx.x * 256 + threadIdx.x;
    if (i >= K * M) return;
    int m = i / K, k = i % K;
    dst[i] = f2bf(src[(size_t)k * M + m]);
}

__global__ void zero_small(int* __restrict__ p, int n) {
    int i = blockIdx.x * 256 + threadIdx.x;
    if (i < n) p[i] = 0;
}

// ---------------- bucketed edge partition (wave-private histograms) ----------
// record = {src | dstlocal<<17, ew}; bucket = dst>>8
__global__ __launch_bounds__(256) void part_k(
    const int* __restrict__ src, const int* __restrict__ dst,
    const float* __restrict__ ew, int* __restrict__ gcur,
    int2* __restrict__ part, int nE, int nbuck) {
    __shared__ int lh[4][NBUCK_MAX];
    __shared__ int gb[4][NBUCK_MAX];
    const int tid = threadIdx.x;
    const int w = tid >> 6;
    for (int t = tid; t < 4 * NBUCK_MAX; t += 256) ((int*)lh)[t] = 0;
    __syncthreads();
    const int e0 = blockIdx.x * 4096;
    int rk[16], bk[16];
#pragma unroll
    for (int j = 0; j < 16; ++j) {
        int e = e0 + j * 256 + tid;
        rk[j] = -1;
        if (e < nE) {
            int b = dst[e] >> BSHIFT;
            bk[j] = b;
            rk[j] = atomicAdd(&lh[w][b], 1);      // wave-private: ~0.2 collisions
        }
    }
    __syncthreads();
    for (int t = tid; t < nbuck; t += 256) {
        int c0 = lh[0][t], c1 = lh[1][t], c2 = lh[2][t], c3 = lh[3][t];
        int tot = c0 + c1 + c2 + c3;
        int base = tot ? atomicAdd(&gcur[t], tot) : 0;
        gb[0][t] = base;
        gb[1][t] = base + c0;
        gb[2][t] = base + c0 + c1;
        gb[3][t] = base + c0 + c1 + c2;
    }
    __syncthreads();
#pragma unroll
    for (int j = 0; j < 16; ++j) {
        int e = e0 + j * 256 + tid;
        if (e >= nE) continue;
        int b = bk[j];
        int slot = gb[w][b] + rk[j];
        if (slot >= 0 && slot < BCAP) {
            int s = src[e];
            int dl = dst[e] & ((1 << BSHIFT) - 1);
            part[(size_t)b * BCAP + slot] = make_int2(s | (dl << 17), __float_as_int(ew[e]));
        }
    }
}

// exclusive scan of clamped bucket counts -> bbase; rp[n] = total
__global__ void scanB(const int* __restrict__ gcur, int* __restrict__ bbase,
                      int* __restrict__ rp, int n, int nbuck) {
    __shared__ int s[512];
    int t = threadIdx.x;
    int c = (t < nbuck) ? gcur[t] : 0;
    if (c > BCAP) c = BCAP;
    s[t] = c;
    __syncthreads();
#pragma unroll
    for (int off = 1; off < 512; off <<= 1) {
        int x = (t >= off) ? s[t - off] : 0;
        __syncthreads();
        s[t] += x;
        __syncthreads();
    }
    if (t < nbuck) bbase[t] = s[t] - c;        // exclusive
    if (t == nbuck - 1) rp[n] = s[t];          // total (== E unless overflow)
}

// one 256-thread block per bucket: LDS counting sort by dstlocal ->
// ev records {src, ew}; fixed-point weighted degree fused -> dinv; rp.
__global__ __launch_bounds__(256) void csr_bucket(
    const int2* __restrict__ part, const int* __restrict__ gcur,
    const int* __restrict__ bbase, int2* __restrict__ ev,
    int* __restrict__ rp, float* __restrict__ dinv, int n) {
    __shared__ int hist[256];
    __shared__ int cur[256];
    __shared__ int wd[256];
    const int b = blockIdx.x;
    const int t = threadIdx.x;
    int cnt = gcur[b];
    if (cnt > BCAP) cnt = BCAP;
    const int gbase = bbase[b];
    const int2* pb = part + (size_t)b * BCAP;

    hist[t] = 0; wd[t] = 0;
    __syncthreads();
    for (int i = t; i < cnt; i += 256)
        atomicAdd(&hist[(pb[i].x >> 17) & 255], 1);
    __syncthreads();
    int myh = hist[t];
#pragma unroll
    for (int off = 1; off < 256; off <<= 1) {
        int x = (t >= off) ? hist[t - off] : 0;
        __syncthreads();
        hist[t] += x;
        __syncthreads();
    }
    int excl = hist[t] - myh;
    cur[t] = excl;
    __syncthreads();
    for (int i = t; i < cnt; i += 256) {
        int2 p = pb[i];
        int dl = (p.x >> 17) & 255;
        int pos = atomicAdd(&cur[dl], 1);
        ev[(size_t)gbase + pos] = make_int2(p.x & 0x1FFFF, p.y);
        atomicAdd(&wd[dl], (int)(__int_as_float(p.y) * WDSCALE + 0.5f));
    }
    __syncthreads();
    int g = (b << BSHIFT) + t;
    if (g < n) {
        dinv[g] = rsqrtf(1.f + (float)wd[t] * (1.f / WDSCALE));
        rp[g] = gbase + excl;
    }
}

// gather: one wave per node, 8-deep ILP.
// aggr = relu( dinv[n]*sum(dinv[src]*ew*h[src]) + dinv[n]^2*h[n] + bias )
__global__ __launch_bounds__(256) void gather_bf(
    const int* __restrict__ rp, const int2* __restrict__ ev,
    const unsigned short* __restrict__ h,
    const float* __restrict__ dinv, const float* __restrict__ bias,
    unsigned short* __restrict__ aggr, int n) {
    int node = (int)(((size_t)blockIdx.x * 256 + threadIdx.x) >> 6);
    if (node >= n) return;
    int lane = threadIdx.x & 63;
    float di = dinv[node];
    float sl = di * di;
    unsigned int hu = *(const unsigned int*)(h + (size_t)node * 128 + lane * 2);
    float2 bv = *(const float2*)(bias + lane * 2);
    float ax0 = 0.f, ay0 = 0.f, ax1 = 0.f, ay1 = 0.f;
    float ax2 = 0.f, ay2 = 0.f, ax3 = 0.f, ay3 = 0.f;
    const int beg = rp[node], end = rp[node + 1];
    int i = beg;
    for (; i + 7 < end; i += 8) {
        int2 e[8];
#pragma unroll
        for (int j = 0; j < 8; ++j) e[j] = ev[i + j];
        float nm[8];
#pragma unroll
        for (int j = 0; j < 8; ++j) nm[j] = dinv[e[j].x] * __int_as_float(e[j].y);
        unsigned int u[8];
#pragma unroll
        for (int j = 0; j < 8; ++j)
            u[j] = *(const unsigned int*)(h + (size_t)e[j].x * 128 + lane * 2);
        ax0 += nm[0] * bflo(u[0]); ay0 += nm[0] * bfhi(u[0]);
        ax1 += nm[1] * bflo(u[1]); ay1 += nm[1] * bfhi(u[1]);
        ax2 += nm[2] * bflo(u[2]); ay2 += nm[2] * bfhi(u[2]);
        ax3 += nm[3] * bflo(u[3]); ay3 += nm[3] * bfhi(u[3]);
        ax0 += nm[4] * bflo(u[4]); ay0 += nm[4] * bfhi(u[4]);
        ax1 += nm[5] * bflo(u[5]); ay1 += nm[5] * bfhi(u[5]);
        ax2 += nm[6] * bflo(u[6]); ay2 += nm[6] * bfhi(u[6]);
        ax3 += nm[7] * bflo(u[7]); ay3 += nm[7] * bfhi(u[7]);
    }
    for (; i + 3 < end; i += 4) {
        int2 e0 = ev[i], e1 = ev[i + 1], e2 = ev[i + 2], e3 = ev[i + 3];
        float n0 = dinv[e0.x] * __int_as_float(e0.y);
        float n1 = dinv[e1.x] * __int_as_float(e1.y);
        float n2 = dinv[e2.x] * __int_as_float(e2.y);
        float n3 = dinv[e3.x] * __int_as_float(e3.y);
        unsigned int u0 = *(const unsigned int*)(h + (size_t)e0.x * 128 + lane * 2);
        unsigned int u1 = *(const unsigned int*)(h + (size_t)e1.x * 128 + lane * 2);
        unsigned int u2 = *(const unsigned int*)(h + (size_t)e2.x * 128 + lane * 2);
        unsigned int u3 = *(const unsigned int*)(h + (size_t)e3.x * 128 + lane * 2);
        ax0 += n0 * bflo(u0); ay0 += n0 * bfhi(u0);
        ax1 += n1 * bflo(u1); ay1 += n1 * bfhi(u1);
        ax2 += n2 * bflo(u2); ay2 += n2 * bfhi(u2);
        ax3 += n3 * bflo(u3); ay3 += n3 * bfhi(u3);
    }
    for (; i < end; ++i) {
        int2 e0 = ev[i];
        float n0 = dinv[e0.x] * __int_as_float(e0.y);
        unsigned int u0 = *(const unsigned int*)(h + (size_t)e0.x * 128 + lane * 2);
        ax0 += n0 * bflo(u0); ay0 += n0 * bfhi(u0);
    }
    float ox = frelu(di * ((ax0 + ax1) + (ax2 + ax3)) + sl * bflo(hu) + bv.x);
    float oy = frelu(di * ((ay0 + ay1) + (ay2 + ay3)) + sl * bfhi(hu) + bv.y);
    unsigned int o = (unsigned int)f2bf(ox) | ((unsigned int)f2bf(oy) << 16);
    *(unsigned int*)(aggr + (size_t)node * 128 + lane * 2) = o;
}

// ---------------- bf16 MFMA GEMM (round-9) ----------------
// BM=128, BK=64, BN in {64,128}. 4 waves: wave tile 64 x BN/2.
// EPI: 0 = bf16 store; 1 = f32 store; 2 = f32 store + xs[row*64+col] += v.
template<int K, int BN, int RELU, int EPI>
__global__ __launch_bounds__(256, 2) void gemm_bf(
    const unsigned short* __restrict__ A, const unsigned short* __restrict__ Wt,
    const float* __restrict__ bias, void* __restrict__ Cout,
    int M, int nrows, float* __restrict__ xs) {
    constexpr int BM = 128, BK = 64;
    constexpr int WN = BN / 2;        // wave cols
    constexpr int NF = WN / 16;       // col fragments per wave (2 or 4)
    static_assert(BN == 64 || BN == 128, "BN");
    __shared__ unsigned short As[BM][BK + 8];
    __shared__ unsigned short Bs[BN][BK + 8];

    const int tid  = threadIdx.x;
    const int wid  = tid >> 6;
    const int lane = tid & 63;
    const int wm   = (wid >> 1) * 64;
    const int wn   = (wid & 1) * WN;
    const int row0 = blockIdx.x * BM;
    const int col0 = blockIdx.y * BN;
    const int lr   = lane & 15;
    const int lk   = (lane >> 4) * 8;

    f32x4 acc[4][NF] = {};

    for (int k0 = 0; k0 < K; k0 += BK) {
#pragma unroll
        for (int it = 0; it < 4; ++it) {                    // A: 128 rows x 8 granules
            int f = tid + it * 256;
            int r = f >> 3, g = f & 7;
            int grow = row0 + r;
            if (grow >= nrows) grow = nrows - 1;
            bf16x8 v = *(const bf16x8*)(A + (size_t)grow * K + k0 + g * 8);
            *(bf16x8*)&As[r][g * 8] = v;
        }
#pragma unroll
        for (int it = 0; it < BN / 32; ++it) {              // B: BN rows x 8 granules
            int f = tid + it * 256;
            int nidx = f >> 3, g = f & 7;
            bf16x8 v = *(const bf16x8*)(Wt + (size_t)(col0 + nidx) * K + k0 + g * 8);
            *(bf16x8*)&Bs[nidx][g * 8] = v;
        }
        __syncthreads();
#pragma unroll
        for (int kk = 0; kk < 2; ++kk) {
            bf16x8 af[4], bfv[NF];
#pragma unroll
            for (int mi = 0; mi < 4; ++mi)
                af[mi] = *(const bf16x8*)&As[wm + 16 * mi + lr][kk * 32 + lk];
#pragma unroll
            for (int ni = 0; ni < NF; ++ni)
                bfv[ni] = *(const bf16x8*)&Bs[wn + 16 * ni + lr][kk * 32 + lk];
#pragma unroll
            for (int mi = 0; mi < 4; ++mi)
#pragma unroll
                for (int ni = 0; ni < NF; ++ni)
                    acc[mi][ni] = __builtin_amdgcn_mfma_f32_16x16x32_bf16(
                        af[mi], bfv[ni], acc[mi][ni], 0, 0, 0);
        }
        __syncthreads();
    }

    const int dr0 = (lane >> 4) * 4;
#pragma unroll
    for (int ni = 0; ni < NF; ++ni) {
        int col = col0 + wn + 16 * ni + lr;
        float bv = bias ? bias[col] : 0.f;
#pragma unroll
        for (int mi = 0; mi < 4; ++mi) {
#pragma unroll
            for (int r = 0; r < 4; ++r) {
                int grow = row0 + wm + 16 * mi + dr0 + r;
                if (grow >= nrows) continue;
                float v = acc[mi][ni][r] + bv;
                if (RELU) v = frelu(v);
                if (EPI == 0) {
                    ((unsigned short*)Cout)[(size_t)grow * M + col] = f2bf(v);
                } else {
                    ((float*)Cout)[(size_t)grow * M + col] = v;
                    if (EPI == 2) xs[(size_t)grow * 64 + col] += v;
                }
            }
        }
    }
}

// ---------------------------------------------------------------------------
extern "C" void kernel_launch(void* const* d_in, const int* in_sizes, int n_in,
                              void* d_out, int out_size, void* d_ws, size_t ws_size,
                              hipStream_t stream) {
    (void)n_in; (void)out_size; (void)ws_size;
    const float* X = (const float*)d_in[0];
    const int N = in_sizes[0] / 128;

    const float* fc1_w1 = (const float*)d_in[19];
    const float* fc1_b1 = (const float*)d_in[20];
    const float* fc1_w2 = (const float*)d_in[21];
    const float* fc1_b2 = (const float*)d_in[22];
    const float* fc1_w3 = (const float*)d_in[23];
    const float* fc1_b3 = (const float*)d_in[24];
    const float* fc2_w1 = (const float*)d_in[25];
    const float* fc2_b1 = (const float*)d_in[26];
    const float* fc2_w2 = (const float*)d_in[27];
    const float* fc2_b2 = (const float*)d_in[28];
    const float* fc2_w3 = (const float*)d_in[29];
    const float* fc2_b3 = (const float*)d_in[30];

    float* out = (float*)d_out;
    float* Xs  = out;  // slot 0

    // ---- workspace layout ----
    char* base = (char*)d_ws;
    const size_t Npad = (((size_t)N + 255) / 256) * 256;
    float*          dinv  = (float*)base;                 base += Npad * 4;
    unsigned short* Xbf   = (unsigned short*)base;        base += (size_t)N * 128 * 2;
    unsigned short* t1bf  = (unsigned short*)base;        base += (size_t)N * 256 * 2;  // CSR arena alias
    unsigned short* t2bf  = (unsigned short*)base;        base += (size_t)N * 128 * 2;
    unsigned short* aggbf = (unsigned short*)base;        base += (size_t)N * 128 * 2;
    unsigned short* wtbuf = (unsigned short*)base;

    unsigned short* fc1w1t = wtbuf;
    unsigned short* fc1w2t = fc1w1t + 32768;
    unsigned short* fc1w3t = fc1w2t + 32768;
    unsigned short* fc2w1t = fc1w3t + 8192;
    unsigned short* fc2w2t = fc2w1t + 32768;
    unsigned short* fc2w3t = fc2w2t + 32768;
    unsigned short* gwt    = fc2w3t + 8192;

    const dim3 blk(256);
    const int GR = (N + 127) / 128;
    const int NBUCK = (N + 255) >> 8;     // 391 for N=100000
    const int GWB = (int)(((size_t)N * 64 + 255) / 256);

    // ---- one-time conversions ----
    xconv<<<(N * 32 + 255) / 256, blk, 0, stream>>>(X, Xbf, N * 32);
    wtrans<<<(128 * 256 + 255) / 256, blk, 0, stream>>>(fc1_w1, fc1w1t, 128, 256);
    wtrans<<<(256 * 128 + 255) / 256, blk, 0, stream>>>(fc1_w2, fc1w2t, 256, 128);
    wtrans<<<(128 * 64 + 255) / 256, blk, 0, stream>>>(fc1_w3, fc1w3t, 128, 64);
    wtrans<<<(128 * 256 + 255) / 256, blk, 0, stream>>>(fc2_w1, fc2w1t, 128, 256);
    wtrans<<<(256 * 128 + 255) / 256, blk, 0, stream>>>(fc2_w2, fc2w2t, 256, 128);
    wtrans<<<(128 * 64 + 255) / 256, blk, 0, stream>>>(fc2_w3, fc2w3t, 128, 64);
    for (int g = 0; g < 3; ++g) {
        wtrans<<<(128 * 128 + 255) / 256, blk, 0, stream>>>(
            (const float*)d_in[3 + 6 * g], gwt + g * 32768, 128, 128);
        wtrans<<<(128 * 128 + 255) / 256, blk, 0, stream>>>(
            (const float*)d_in[5 + 6 * g], gwt + g * 32768 + 16384, 128, 128);
    }

    // ---- X0 = fc1(X) -> Xs ----
    gemm_bf<128, 128, 1, 0><<<dim3(GR, 2), blk, 0, stream>>>(Xbf, fc1w1t, fc1_b1, t1bf, 256, N, nullptr);
    gemm_bf<256, 128, 1, 0><<<dim3(GR, 1), blk, 0, stream>>>(t1bf, fc1w2t, fc1_b2, t2bf, 128, N, nullptr);
    gemm_bf<128, 64, 1, 1><<<dim3(GR, 1), blk, 0, stream>>>(t2bf, fc1w3t, fc1_b3, Xs, 64, N, nullptr);

    // ---- graphs ----
    for (int g = 0; g < 3; ++g) {
        const int*   ei  = (const int*)d_in[1 + 6 * g];
        const int    E   = in_sizes[1 + 6 * g] / 2;
        const int*   srp = ei;
        const int*   dsp = ei + E;
        const float* ew  = (const float*)d_in[2 + 6 * g];
        const float* b1  = (const float*)d_in[4 + 6 * g];
        const float* b2  = (const float*)d_in[6 + 6 * g];
        unsigned short* w1t = gwt + g * 32768;
        unsigned short* w2t = w1t + 16384;

        // CSR arena aliases t1bf (dead during conv phase)
        int2* part  = (int2*)t1bf;                        // NBUCK * BCAP  (19.2 MB)
        int2* ev    = part + (size_t)NBUCK * BCAP;        // E             (12.8 MB)
        int*  rpn   = (int*)(ev + E);                     // N+1
        int*  gcur  = rpn + (N + 1);                      // NBUCK
        int*  bbase = gcur + NBUCK;                       // NBUCK

        zero_small<<<(NBUCK + 255) / 256, blk, 0, stream>>>(gcur, NBUCK);
        part_k<<<(E + 4095) / 4096, blk, 0, stream>>>(srp, dsp, ew, gcur, part, E, NBUCK);
        scanB<<<1, 512, 0, stream>>>(gcur, bbase, rpn, N, NBUCK);
        csr_bucket<<<NBUCK, blk, 0, stream>>>(part, gcur, bbase, ev, rpn, dinv, N);

        // conv1 + conv2 (gather applies dinv scaling + self-loop + bias + relu)
        gemm_bf<128, 128, 0, 0><<<dim3(GR, 1), blk, 0, stream>>>(Xbf, w1t, nullptr, t2bf, 128, N, nullptr);
        gather_bf<<<GWB, blk, 0, stream>>>(rpn, ev, t2bf, dinv, b1, aggbf, N);
        gemm_bf<128, 128, 0, 0><<<dim3(GR, 1), blk, 0, stream>>>(aggbf, w2t, nullptr, t2bf, 128, N, nullptr);
        gather_bf<<<GWB, blk, 0, stream>>>(rpn, ev, t2bf, dinv, b2, aggbf, N);

        // fc2 head
        gemm_bf<128, 128, 1, 0><<<dim3(GR, 2), blk, 0, stream>>>(aggbf, fc2w1t, fc2_b1, t1bf, 256, N, nullptr);
        gemm_bf<256, 128, 1, 0><<<dim3(GR, 1), blk, 0, stream>>>(t1bf, fc2w2t, fc2_b2, t2bf, 128, N, nullptr);
        gemm_bf<128, 64, 1, 2><<<dim3(GR, 1), blk, 0, stream>>>(
            t2bf, fc2w3t, fc2_b3, out + (size_t)(1 + g) * N * 64, 64, N, Xs);
    }
}

// Round 12
// 970.836 us; speedup vs baseline: 1.2312x; 1.1316x over previous
//
#include <hip/hip_runtime.h>

// ---------------------------------------------------------------------------
// SubModel_22016002359901: 3x GCN(2 conv) + FC heads, N=100000, F=128, E=1.6M
// Round 12: fuse each fc chain (128->256->128->64, 3 GEMMs) into ONE kernel
// holding t1/t2 in LDS (70KB, 2 blocks/CU) -- deletes 614MB of intermediate
// write+read traffic and 8 dispatches. conv GEMMs / CSR build / gather
// unchanged from round 11 (best, 1098us).
// ---------------------------------------------------------------------------

typedef short bf16x8 __attribute__((ext_vector_type(8)));
typedef float f32x4 __attribute__((ext_vector_type(4)));

#define BSHIFT 8                 // 256 dst nodes per bucket
#define NBUCK_MAX 400
#define BCAP 6144                // mean 4096 @ E=1.6M, sigma ~64 -> 32 sigma headroom
#define WDSCALE 8388608.f        // 2^23 fixed-point for weighted degree

static __device__ __forceinline__ float frelu(float x) { return x > 0.f ? x : 0.f; }

static __device__ __forceinline__ unsigned short f2bf(float f) {
    unsigned int u = __float_as_uint(f);
    u += 0x7fffu + ((u >> 16) & 1u);           // RNE
    return (unsigned short)(u >> 16);
}
static __device__ __forceinline__ float bflo(unsigned int u) {
    return __uint_as_float(u << 16);
}
static __device__ __forceinline__ float bfhi(unsigned int u) {
    return __uint_as_float(u & 0xffff0000u);
}

// ---------------- conversion kernels ----------------
__global__ void xconv(const float* __restrict__ src, unsigned short* __restrict__ dst, int n4) {
    int i = blockIdx.x * 256 + threadIdx.x;
    if (i >= n4) return;
    float4 v = *(const float4*)(src + (size_t)i * 4);
    ushort4 o = {f2bf(v.x), f2bf(v.y), f2bf(v.z), f2bf(v.w)};
    *(ushort4*)(dst + (size_t)i * 4) = o;
}

__global__ void wtrans(const float* __restrict__ src, unsigned short* __restrict__ dst,
                       int K, int M) {
    int i = blockIdx.x * 256 + threadIdx.x;
    if (i >= K * M) return;
    int m = i / K, k = i % K;
    dst[i] = f2bf(src[(size_t)k * M + m]);
}

__global__ void zero_small(int* __restrict__ p, int n) {
    int i = blockIdx.x * 256 + threadIdx.x;
    if (i < n) p[i] = 0;
}

// ---------------- bucketed edge partition (wave-private histograms) ----------
__global__ __launch_bounds__(256) void part_k(
    const int* __restrict__ src, const int* __restrict__ dst,
    const float* __restrict__ ew, int* __restrict__ gcur,
    int2* __restrict__ part, int nE, int nbuck) {
    __shared__ int lh[4][NBUCK_MAX];
    __shared__ int gb[4][NBUCK_MAX];
    const int tid = threadIdx.x;
    const int w = tid >> 6;
    for (int t = tid; t < 4 * NBUCK_MAX; t += 256) ((int*)lh)[t] = 0;
    __syncthreads();
    const int e0 = blockIdx.x * 4096;
    int rk[16], bk[16];
#pragma unroll
    for (int j = 0; j < 16; ++j) {
        int e = e0 + j * 256 + tid;
        rk[j] = -1;
        if (e < nE) {
            int b = dst[e] >> BSHIFT;
            bk[j] = b;
            rk[j] = atomicAdd(&lh[w][b], 1);
        }
    }
    __syncthreads();
    for (int t = tid; t < nbuck; t += 256) {
        int c0 = lh[0][t], c1 = lh[1][t], c2 = lh[2][t], c3 = lh[3][t];
        int tot = c0 + c1 + c2 + c3;
        int base = tot ? atomicAdd(&gcur[t], tot) : 0;
        gb[0][t] = base;
        gb[1][t] = base + c0;
        gb[2][t] = base + c0 + c1;
        gb[3][t] = base + c0 + c1 + c2;
    }
    __syncthreads();
#pragma unroll
    for (int j = 0; j < 16; ++j) {
        int e = e0 + j * 256 + tid;
        if (e >= nE) continue;
        int b = bk[j];
        int slot = gb[w][b] + rk[j];
        if (slot >= 0 && slot < BCAP) {
            int s = src[e];
            int dl = dst[e] & ((1 << BSHIFT) - 1);
            part[(size_t)b * BCAP + slot] = make_int2(s | (dl << 17), __float_as_int(ew[e]));
        }
    }
}

// exclusive scan of clamped bucket counts -> bbase; rp[n] = total
__global__ void scanB(const int* __restrict__ gcur, int* __restrict__ bbase,
                      int* __restrict__ rp, int n, int nbuck) {
    __shared__ int s[512];
    int t = threadIdx.x;
    int c = (t < nbuck) ? gcur[t] : 0;
    if (c > BCAP) c = BCAP;
    s[t] = c;
    __syncthreads();
#pragma unroll
    for (int off = 1; off < 512; off <<= 1) {
        int x = (t >= off) ? s[t - off] : 0;
        __syncthreads();
        s[t] += x;
        __syncthreads();
    }
    if (t < nbuck) bbase[t] = s[t] - c;
    if (t == nbuck - 1) rp[n] = s[t];
}

// one 256-thread block per bucket: LDS counting sort by dstlocal
__global__ __launch_bounds__(256) void csr_bucket(
    const int2* __restrict__ part, const int* __restrict__ gcur,
    const int* __restrict__ bbase, int2* __restrict__ ev,
    int* __restrict__ rp, float* __restrict__ dinv, int n) {
    __shared__ int hist[256];
    __shared__ int cur[256];
    __shared__ int wd[256];
    const int b = blockIdx.x;
    const int t = threadIdx.x;
    int cnt = gcur[b];
    if (cnt > BCAP) cnt = BCAP;
    const int gbase = bbase[b];
    const int2* pb = part + (size_t)b * BCAP;

    hist[t] = 0; wd[t] = 0;
    __syncthreads();
    for (int i = t; i < cnt; i += 256)
        atomicAdd(&hist[(pb[i].x >> 17) & 255], 1);
    __syncthreads();
    int myh = hist[t];
#pragma unroll
    for (int off = 1; off < 256; off <<= 1) {
        int x = (t >= off) ? hist[t - off] : 0;
        __syncthreads();
        hist[t] += x;
        __syncthreads();
    }
    int excl = hist[t] - myh;
    cur[t] = excl;
    __syncthreads();
    for (int i = t; i < cnt; i += 256) {
        int2 p = pb[i];
        int dl = (p.x >> 17) & 255;
        int pos = atomicAdd(&cur[dl], 1);
        ev[(size_t)gbase + pos] = make_int2(p.x & 0x1FFFF, p.y);
        atomicAdd(&wd[dl], (int)(__int_as_float(p.y) * WDSCALE + 0.5f));
    }
    __syncthreads();
    int g = (b << BSHIFT) + t;
    if (g < n) {
        dinv[g] = rsqrtf(1.f + (float)wd[t] * (1.f / WDSCALE));
        rp[g] = gbase + excl;
    }
}

// gather: one wave per node, 8-deep ILP (round-11, 76us)
__global__ __launch_bounds__(256) void gather_bf(
    const int* __restrict__ rp, const int2* __restrict__ ev,
    const unsigned short* __restrict__ h,
    const float* __restrict__ dinv, const float* __restrict__ bias,
    unsigned short* __restrict__ aggr, int n) {
    int node = (int)(((size_t)blockIdx.x * 256 + threadIdx.x) >> 6);
    if (node >= n) return;
    int lane = threadIdx.x & 63;
    float di = dinv[node];
    float sl = di * di;
    unsigned int hu = *(const unsigned int*)(h + (size_t)node * 128 + lane * 2);
    float2 bv = *(const float2*)(bias + lane * 2);
    float ax0 = 0.f, ay0 = 0.f, ax1 = 0.f, ay1 = 0.f;
    float ax2 = 0.f, ay2 = 0.f, ax3 = 0.f, ay3 = 0.f;
    const int beg = rp[node], end = rp[node + 1];
    int i = beg;
    for (; i + 7 < end; i += 8) {
        int2 e[8];
#pragma unroll
        for (int j = 0; j < 8; ++j) e[j] = ev[i + j];
        float nm[8];
#pragma unroll
        for (int j = 0; j < 8; ++j) nm[j] = dinv[e[j].x] * __int_as_float(e[j].y);
        unsigned int u[8];
#pragma unroll
        for (int j = 0; j < 8; ++j)
            u[j] = *(const unsigned int*)(h + (size_t)e[j].x * 128 + lane * 2);
        ax0 += nm[0] * bflo(u[0]); ay0 += nm[0] * bfhi(u[0]);
        ax1 += nm[1] * bflo(u[1]); ay1 += nm[1] * bfhi(u[1]);
        ax2 += nm[2] * bflo(u[2]); ay2 += nm[2] * bfhi(u[2]);
        ax3 += nm[3] * bflo(u[3]); ay3 += nm[3] * bfhi(u[3]);
        ax0 += nm[4] * bflo(u[4]); ay0 += nm[4] * bfhi(u[4]);
        ax1 += nm[5] * bflo(u[5]); ay1 += nm[5] * bfhi(u[5]);
        ax2 += nm[6] * bflo(u[6]); ay2 += nm[6] * bfhi(u[6]);
        ax3 += nm[7] * bflo(u[7]); ay3 += nm[7] * bfhi(u[7]);
    }
    for (; i + 3 < end; i += 4) {
        int2 e0 = ev[i], e1 = ev[i + 1], e2 = ev[i + 2], e3 = ev[i + 3];
        float n0 = dinv[e0.x] * __int_as_float(e0.y);
        float n1 = dinv[e1.x] * __int_as_float(e1.y);
        float n2 = dinv[e2.x] * __int_as_float(e2.y);
        float n3 = dinv[e3.x] * __int_as_float(e3.y);
        unsigned int u0 = *(const unsigned int*)(h + (size_t)e0.x * 128 + lane * 2);
        unsigned int u1 = *(const unsigned int*)(h + (size_t)e1.x * 128 + lane * 2);
        unsigned int u2 = *(const unsigned int*)(h + (size_t)e2.x * 128 + lane * 2);
        unsigned int u3 = *(const unsigned int*)(h + (size_t)e3.x * 128 + lane * 2);
        ax0 += n0 * bflo(u0); ay0 += n0 * bfhi(u0);
        ax1 += n1 * bflo(u1); ay1 += n1 * bfhi(u1);
        ax2 += n2 * bflo(u2); ay2 += n2 * bfhi(u2);
        ax3 += n3 * bflo(u3); ay3 += n3 * bfhi(u3);
    }
    for (; i < end; ++i) {
        int2 e0 = ev[i];
        float n0 = dinv[e0.x] * __int_as_float(e0.y);
        unsigned int u0 = *(const unsigned int*)(h + (size_t)e0.x * 128 + lane * 2);
        ax0 += n0 * bflo(u0); ay0 += n0 * bfhi(u0);
    }
    float ox = frelu(di * ((ax0 + ax1) + (ax2 + ax3)) + sl * bflo(hu) + bv.x);
    float oy = frelu(di * ((ay0 + ay1) + (ay2 + ay3)) + sl * bfhi(hu) + bv.y);
    unsigned int o = (unsigned int)f2bf(ox) | ((unsigned int)f2bf(oy) << 16);
    *(unsigned int*)(aggr + (size_t)node * 128 + lane * 2) = o;
}

// ---------------- conv GEMM (round-9/11 gemm_bf, BN=128 only) ----------------
template<int K, int BN, int RELU, int EPI>
__global__ __launch_bounds__(256, 2) void gemm_bf(
    const unsigned short* __restrict__ A, const unsigned short* __restrict__ Wt,
    const float* __restrict__ bias, void* __restrict__ Cout,
    int M, int nrows, float* __restrict__ xs) {
    constexpr int BM = 128, BK = 64;
    constexpr int WN = BN / 2;
    constexpr int NF = WN / 16;
    static_assert(BN == 64 || BN == 128, "BN");
    __shared__ unsigned short As[BM][BK + 8];
    __shared__ unsigned short Bs[BN][BK + 8];

    const int tid  = threadIdx.x;
    const int wid  = tid >> 6;
    const int lane = tid & 63;
    const int wm   = (wid >> 1) * 64;
    const int wn   = (wid & 1) * WN;
    const int row0 = blockIdx.x * BM;
    const int col0 = blockIdx.y * BN;
    const int lr   = lane & 15;
    const int lk   = (lane >> 4) * 8;

    f32x4 acc[4][NF] = {};

    for (int k0 = 0; k0 < K; k0 += BK) {
#pragma unroll
        for (int it = 0; it < 4; ++it) {
            int f = tid + it * 256;
            int r = f >> 3, g = f & 7;
            int grow = row0 + r;
            if (grow >= nrows) grow = nrows - 1;
            bf16x8 v = *(const bf16x8*)(A + (size_t)grow * K + k0 + g * 8);
            *(bf16x8*)&As[r][g * 8] = v;
        }
#pragma unroll
        for (int it = 0; it < BN / 32; ++it) {
            int f = tid + it * 256;
            int nidx = f >> 3, g = f & 7;
            bf16x8 v = *(const bf16x8*)(Wt + (size_t)(col0 + nidx) * K + k0 + g * 8);
            *(bf16x8*)&Bs[nidx][g * 8] = v;
        }
        __syncthreads();
#pragma unroll
        for (int kk = 0; kk < 2; ++kk) {
            bf16x8 af[4], bfv[NF];
#pragma unroll
            for (int mi = 0; mi < 4; ++mi)
                af[mi] = *(const bf16x8*)&As[wm + 16 * mi + lr][kk * 32 + lk];
#pragma unroll
            for (int ni = 0; ni < NF; ++ni)
                bfv[ni] = *(const bf16x8*)&Bs[wn + 16 * ni + lr][kk * 32 + lk];
#pragma unroll
            for (int mi = 0; mi < 4; ++mi)
#pragma unroll
                for (int ni = 0; ni < NF; ++ni)
                    acc[mi][ni] = __builtin_amdgcn_mfma_f32_16x16x32_bf16(
                        af[mi], bfv[ni], acc[mi][ni], 0, 0, 0);
        }
        __syncthreads();
    }

    const int dr0 = (lane >> 4) * 4;
#pragma unroll
    for (int ni = 0; ni < NF; ++ni) {
        int col = col0 + wn + 16 * ni + lr;
        float bv = bias ? bias[col] : 0.f;
#pragma unroll
        for (int mi = 0; mi < 4; ++mi) {
#pragma unroll
            for (int r = 0; r < 4; ++r) {
                int grow = row0 + wm + 16 * mi + dr0 + r;
                if (grow >= nrows) continue;
                float v = acc[mi][ni][r] + bv;
                if (RELU) v = frelu(v);
                if (EPI == 0) {
                    ((unsigned short*)Cout)[(size_t)grow * M + col] = f2bf(v);
                } else {
                    ((float*)Cout)[(size_t)grow * M + col] = v;
                    if (EPI == 2) xs[(size_t)grow * 64 + col] += v;
                }
            }
        }
    }
}

// ---------------- fused fc chain: in[128] ->256 ->128 ->64 ----------------
// out = relu(relu(relu(A@W1+b1)@W2+b2)@W3+b3); EPI: 1 = store f32; 2 = +xs.
// LDS: Ain 34.8KB (input, later T2) + T1q 18.4KB + Bst 18.4KB = 70KB -> 2/CU.
template<int EPI>
__global__ __launch_bounds__(256, 2) void fc_chain(
    const unsigned short* __restrict__ A,
    const unsigned short* __restrict__ W1t, const float* __restrict__ b1,
    const unsigned short* __restrict__ W2t, const float* __restrict__ b2,
    const unsigned short* __restrict__ W3t, const float* __restrict__ b3,
    float* __restrict__ Cout, int nrows, float* __restrict__ xs) {
    __shared__ unsigned short Ain[128 * 136];   // [128][136] input tile / T2
    __shared__ unsigned short T1q[128 * 72];    // [128][72] t1 col-slice
    __shared__ unsigned short Bst[128 * 72];    // B staging ([64][136] or [128][72])

    const int tid  = threadIdx.x;
    const int wid  = tid >> 6;
    const int lane = tid & 63;
    const int wm   = (wid >> 1) * 64;
    const int wnH  = (wid & 1) * 32;   // half-width (GEMM1 / GEMM3)
    const int wnF  = (wid & 1) * 64;   // full-width (GEMM2)
    const int row0 = blockIdx.x * 128;
    const int lr   = lane & 15;
    const int lk   = (lane >> 4) * 8;
    const int dr0  = (lane >> 4) * 4;

    // stage input tile (128 rows x K=128)
#pragma unroll
    for (int it = 0; it < 8; ++it) {
        int f = tid + it * 256;
        int r = f >> 4, g = f & 15;
        int grow = row0 + r; if (grow >= nrows) grow = nrows - 1;
        *(bf16x8*)&Ain[r * 136 + g * 8] =
            *(const bf16x8*)(A + (size_t)grow * 128 + g * 8);
    }

    f32x4 acc2[4][4] = {};

    for (int q = 0; q < 4; ++q) {
        __syncthreads();                     // prior Bst/T1q consumers done
        // stage W1 rows q*64.. (64 x 128) -> Bst[64][136]
#pragma unroll
        for (int it = 0; it < 4; ++it) {
            int f = tid + it * 256;
            int r = f >> 4, g = f & 15;
            *(bf16x8*)&Bst[r * 136 + g * 8] =
                *(const bf16x8*)(W1t + (size_t)(q * 64 + r) * 128 + g * 8);
        }
        __syncthreads();
        // GEMM1 slice: acc1 = Ain @ W1slice  (128 x 64)
        f32x4 acc1[4][2] = {};
#pragma unroll
        for (int kk = 0; kk < 4; ++kk) {
            bf16x8 af[4], bw[2];
#pragma unroll
            for (int mi = 0; mi < 4; ++mi)
                af[mi] = *(const bf16x8*)&Ain[(wm + 16 * mi + lr) * 136 + kk * 32 + lk];
#pragma unroll
            for (int ni = 0; ni < 2; ++ni)
                bw[ni] = *(const bf16x8*)&Bst[(wnH + 16 * ni + lr) * 136 + kk * 32 + lk];
#pragma unroll
            for (int mi = 0; mi < 4; ++mi)
#pragma unroll
                for (int ni = 0; ni < 2; ++ni)
                    acc1[mi][ni] = __builtin_amdgcn_mfma_f32_16x16x32_bf16(
                        af[mi], bw[ni], acc1[mi][ni], 0, 0, 0);
        }
        __syncthreads();                     // Bst readers done; T1q free
        // T1q = relu(acc1 + b1) ; stage W2 k-slice -> Bst[128][72]
#pragma unroll
        for (int ni = 0; ni < 2; ++ni) {
            float bv = b1[q * 64 + wnH + 16 * ni + lr];
#pragma unroll
            for (int mi = 0; mi < 4; ++mi)
#pragma unroll
                for (int r = 0; r < 4; ++r)
                    T1q[(wm + 16 * mi + dr0 + r) * 72 + wnH + 16 * ni + lr] =
                        f2bf(frelu(acc1[mi][ni][r] + bv));
        }
#pragma unroll
        for (int it = 0; it < 4; ++it) {
            int f = tid + it * 256;
            int r = f >> 3, g = f & 7;
            *(bf16x8*)&Bst[r * 72 + g * 8] =
                *(const bf16x8*)(W2t + (size_t)r * 256 + q * 64 + g * 8);
        }
        __syncthreads();
        // GEMM2 partial: acc2 += T1q @ W2slice  (128 x 128, K=64)
#pragma unroll
        for (int kk = 0; kk < 2; ++kk) {
            bf16x8 af[4], bw[4];
#pragma unroll
            for (int mi = 0; mi < 4; ++mi)
                af[mi] = *(const bf16x8*)&T1q[(wm + 16 * mi + lr) * 72 + kk * 32 + lk];
#pragma unroll
            for (int ni = 0; ni < 4; ++ni)
                bw[ni] = *(const bf16x8*)&Bst[(wnF + 16 * ni + lr) * 72 + kk * 32 + lk];
#pragma unroll
            for (int mi = 0; mi < 4; ++mi)
#pragma unroll
                for (int ni = 0; ni < 4; ++ni)
                    acc2[mi][ni] = __builtin_amdgcn_mfma_f32_16x16x32_bf16(
                        af[mi], bw[ni], acc2[mi][ni], 0, 0, 0);
        }
    }
    __syncthreads();                         // all GEMM1/GEMM2 reads done
    // T2 = relu(acc2 + b2) -> Ain (reuse); stage W3 (64 x 128) -> Bst[64][136]
#pragma unroll
    for (int ni = 0; ni < 4; ++ni) {
        float bv = b2[wnF + 16 * ni + lr];
#pragma unroll
        for (int mi = 0; mi < 4; ++mi)
#pragma unroll
            for (int r = 0; r < 4; ++r)
                Ain[(wm + 16 * mi + dr0 + r) * 136 + wnF + 16 * ni + lr] =
                    f2bf(frelu(acc2[mi][ni][r] + bv));
    }
#pragma unroll
    for (int it = 0; it < 4; ++it) {
        int f = tid + it * 256;
        int r = f >> 4, g = f & 15;
        *(bf16x8*)&Bst[r * 136 + g * 8] =
            *(const bf16x8*)(W3t + (size_t)r * 128 + g * 8);
    }
    __syncthreads();
    // GEMM3: acc3 = T2 @ W3  (128 x 64)
    f32x4 acc3[4][2] = {};
#pragma unroll
    for (int kk = 0; kk < 4; ++kk) {
        bf16x8 af[4], bw[2];
#pragma unroll
        for (int mi = 0; mi < 4; ++mi)
            af[mi] = *(const bf16x8*)&Ain[(wm + 16 * mi + lr) * 136 + kk * 32 + lk];
#pragma unroll
        for (int ni = 0; ni < 2; ++ni)
            bw[ni] = *(const bf16x8*)&Bst[(wnH + 16 * ni + lr) * 136 + kk * 32 + lk];
#pragma unroll
        for (int mi = 0; mi < 4; ++mi)
#pragma unroll
            for (int ni = 0; ni < 2; ++ni)
                acc3[mi][ni] = __builtin_amdgcn_mfma_f32_16x16x32_bf16(
                    af[mi], bw[ni], acc3[mi][ni], 0, 0, 0);
    }
    // epilogue
#pragma unroll
    for (int ni = 0; ni < 2; ++ni) {
        int col = wnH + 16 * ni + lr;
        float bv = b3[col];
#pragma unroll
        for (int mi = 0; mi < 4; ++mi)
#pragma unroll
            for (int r = 0; r < 4; ++r) {
                int grow = row0 + wm + 16 * mi + dr0 + r;
                if (grow >= nrows) continue;
                float v = frelu(acc3[mi][ni][r] + bv);
                Cout[(size_t)grow * 64 + col] = v;
                if (EPI == 2) xs[(size_t)grow * 64 + col] += v;
            }
    }
}

// ---------------------------------------------------------------------------
extern "C" void kernel_launch(void* const* d_in, const int* in_sizes, int n_in,
                              void* d_out, int out_size, void* d_ws, size_t ws_size,
                              hipStream_t stream) {
    (void)n_in; (void)out_size; (void)ws_size;
    const float* X = (const float*)d_in[0];
    const int N = in_sizes[0] / 128;

    const float* fc1_w1 = (const float*)d_in[19];
    const float* fc1_b1 = (const float*)d_in[20];
    const float* fc1_w2 = (const float*)d_in[21];
    const float* fc1_b2 = (const float*)d_in[22];
    const float* fc1_w3 = (const float*)d_in[23];
    const float* fc1_b3 = (const float*)d_in[24];
    const float* fc2_w1 = (const float*)d_in[25];
    const float* fc2_b1 = (const float*)d_in[26];
    const float* fc2_w2 = (const float*)d_in[27];
    const float* fc2_b2 = (const float*)d_in[28];
    const float* fc2_w3 = (const float*)d_in[29];
    const float* fc2_b3 = (const float*)d_in[30];

    float* out = (float*)d_out;
    float* Xs  = out;  // slot 0

    // ---- workspace layout ----
    char* base = (char*)d_ws;
    const size_t Npad = (((size_t)N + 255) / 256) * 256;
    float*          dinv  = (float*)base;                 base += Npad * 4;
    unsigned short* Xbf   = (unsigned short*)base;        base += (size_t)N * 128 * 2;
    unsigned short* t1bf  = (unsigned short*)base;        base += (size_t)N * 256 * 2;  // CSR arena
    unsigned short* t2bf  = (unsigned short*)base;        base += (size_t)N * 128 * 2;
    unsigned short* aggbf = (unsigned short*)base;        base += (size_t)N * 128 * 2;
    unsigned short* wtbuf = (unsigned short*)base;

    unsigned short* fc1w1t = wtbuf;
    unsigned short* fc1w2t = fc1w1t + 32768;
    unsigned short* fc1w3t = fc1w2t + 32768;
    unsigned short* fc2w1t = fc1w3t + 8192;
    unsigned short* fc2w2t = fc2w1t + 32768;
    unsigned short* fc2w3t = fc2w2t + 32768;
    unsigned short* gwt    = fc2w3t + 8192;

    const dim3 blk(256);
    const int GR = (N + 127) / 128;
    const int NBUCK = (N + 255) >> 8;     // 391 for N=100000
    const int GWB = (int)(((size_t)N * 64 + 255) / 256);

    // ---- one-time conversions ----
    xconv<<<(N * 32 + 255) / 256, blk, 0, stream>>>(X, Xbf, N * 32);
    wtrans<<<(128 * 256 + 255) / 256, blk, 0, stream>>>(fc1_w1, fc1w1t, 128, 256);
    wtrans<<<(256 * 128 + 255) / 256, blk, 0, stream>>>(fc1_w2, fc1w2t, 256, 128);
    wtrans<<<(128 * 64 + 255) / 256, blk, 0, stream>>>(fc1_w3, fc1w3t, 128, 64);
    wtrans<<<(128 * 256 + 255) / 256, blk, 0, stream>>>(fc2_w1, fc2w1t, 128, 256);
    wtrans<<<(256 * 128 + 255) / 256, blk, 0, stream>>>(fc2_w2, fc2w2t, 256, 128);
    wtrans<<<(128 * 64 + 255) / 256, blk, 0, stream>>>(fc2_w3, fc2w3t, 128, 64);
    for (int g = 0; g < 3; ++g) {
        wtrans<<<(128 * 128 + 255) / 256, blk, 0, stream>>>(
            (const float*)d_in[3 + 6 * g], gwt + g * 32768, 128, 128);
        wtrans<<<(128 * 128 + 255) / 256, blk, 0, stream>>>(
            (const float*)d_in[5 + 6 * g], gwt + g * 32768 + 16384, 128, 128);
    }

    // ---- X0 = fc1(X) -> Xs (fused chain) ----
    fc_chain<1><<<GR, blk, 0, stream>>>(Xbf, fc1w1t, fc1_b1, fc1w2t, fc1_b2,
                                        fc1w3t, fc1_b3, Xs, N, nullptr);

    // ---- graphs ----
    for (int g = 0; g < 3; ++g) {
        const int*   ei  = (const int*)d_in[1 + 6 * g];
        const int    E   = in_sizes[1 + 6 * g] / 2;
        const int*   srp = ei;
        const int*   dsp = ei + E;
        const float* ew  = (const float*)d_in[2 + 6 * g];
        const float* b1  = (const float*)d_in[4 + 6 * g];
        const float* b2  = (const float*)d_in[6 + 6 * g];
        unsigned short* w1t = gwt + g * 32768;
        unsigned short* w2t = w1t + 16384;

        // CSR arena aliases t1bf
        int2* part  = (int2*)t1bf;                        // NBUCK * BCAP
        int2* ev    = part + (size_t)NBUCK * BCAP;        // E
        int*  rpn   = (int*)(ev + E);                     // N+1
        int*  gcur  = rpn + (N + 1);                      // NBUCK
        int*  bbase = gcur + NBUCK;                       // NBUCK

        zero_small<<<(NBUCK + 255) / 256, blk, 0, stream>>>(gcur, NBUCK);
        part_k<<<(E + 4095) / 4096, blk, 0, stream>>>(srp, dsp, ew, gcur, part, E, NBUCK);
        scanB<<<1, 512, 0, stream>>>(gcur, bbase, rpn, N, NBUCK);
        csr_bucket<<<NBUCK, blk, 0, stream>>>(part, gcur, bbase, ev, rpn, dinv, N);

        // conv1 + conv2
        gemm_bf<128, 128, 0, 0><<<dim3(GR, 1), blk, 0, stream>>>(Xbf, w1t, nullptr, t2bf, 128, N, nullptr);
        gather_bf<<<GWB, blk, 0, stream>>>(rpn, ev, t2bf, dinv, b1, aggbf, N);
        gemm_bf<128, 128, 0, 0><<<dim3(GR, 1), blk, 0, stream>>>(aggbf, w2t, nullptr, t2bf, 128, N, nullptr);
        gather_bf<<<GWB, blk, 0, stream>>>(rpn, ev, t2bf, dinv, b2, aggbf, N);

        // fc2 head (fused chain, xs accumulate)
        fc_chain<2><<<GR, blk, 0, stream>>>(aggbf, fc2w1t, fc2_b1, fc2w2t, fc2_b2,
                                            fc2w3t, fc2_b3,
                                            out + (size_t)(1 + g) * N * 64, N, Xs);
    }
}